// Round 3
// baseline (641.806 us; speedup 1.0000x reference)
//
#include <hip/hip_runtime.h>
#include <cstdint>

typedef unsigned short u16;
typedef __attribute__((ext_vector_type(8))) __bf16 bf16x8;
typedef __attribute__((ext_vector_type(4))) float f32x4;

#define S_LEN 2048

__device__ __forceinline__ u16 f2bf(float f) {
  uint32_t u = __builtin_bit_cast(uint32_t, f);
  u += 0x7fffu + ((u >> 16) & 1u);
  return (u16)(u >> 16);
}
__device__ __forceinline__ float bf2f(u16 h) {
  return __builtin_bit_cast(float, (uint32_t)h << 16);
}
__device__ __forceinline__ bf16x8 ldfrag(const u16* p) {
  return __builtin_bit_cast(bf16x8, *(const uint4*)p);
}
__device__ __forceinline__ f32x4 mfma16(bf16x8 a, bf16x8 b, f32x4 c) {
  return __builtin_amdgcn_mfma_f32_16x16x32_bf16(a, b, c, 0, 0, 0);
}

// ---------------- fp32 -> bf16 convert (vectorized) ----------------
__global__ __launch_bounds__(256) void cvt_kernel(const float* __restrict__ in,
                                                  u16* __restrict__ out, int n4) {
  int i = blockIdx.x * 256 + threadIdx.x;
  if (i >= n4) return;
  float4 v = ((const float4*)in)[i];
  ushort4 o;
  o.x = f2bf(v.x); o.y = f2bf(v.y); o.z = f2bf(v.z); o.w = f2bf(v.w);
  ((ushort4*)out)[i] = o;
}

// ------------- fp32 W[K][N] -> bf16 Wt[N][K] (transpose-convert) -------------
__global__ __launch_bounds__(256) void cvtT_kernel(const float* __restrict__ W,
                                                   u16* __restrict__ Wt, int K, int N) {
  __shared__ float t[32][33];
  int tx = threadIdx.x & 31, ty = threadIdx.x >> 5;  // ty 0..7
  int n0 = blockIdx.x * 32, k0 = blockIdx.y * 32;
#pragma unroll
  for (int j = 0; j < 4; ++j)
    t[ty + 8 * j][tx] = W[(long)(k0 + ty + 8 * j) * N + n0 + tx];
  __syncthreads();
#pragma unroll
  for (int j = 0; j < 4; ++j)
    Wt[(long)(n0 + ty + 8 * j) * K + k0 + tx] = f2bf(t[tx][ty + 8 * j]);
}

// ------------- GEMM: C[M][ldc] = A[M][K](bf16) * Bt[N][K]^T(bf16) -------------
// 128x128 tile, 4 waves (2x2), BK=32, LDS k-stride padded to 40 elems.
#define LDT 40
template <int BF16OUT>
__global__ __launch_bounds__(256) void gemm_bt(const u16* __restrict__ A,
                                               const u16* __restrict__ Bt,
                                               void* __restrict__ C, int K, int ldc) {
  __shared__ u16 As[128 * LDT];
  __shared__ u16 Bs[128 * LDT];
  int tid = threadIdx.x;
  int lane = tid & 63, w = tid >> 6;
  int wr = (w >> 1) * 64, wc = (w & 1) * 64;
  int l15 = lane & 15, l4 = lane >> 4;
  int rowbase = blockIdx.x * 128, colbase = blockIdx.y * 128;
  f32x4 acc[4][4] = {};
  int r0 = tid >> 2, kc0 = (tid & 3) * 8;
  const u16* Ap = A + (long)(rowbase + r0) * K + kc0;
  const u16* Bp = Bt + (long)(colbase + r0) * K + kc0;
  u16* Asw = &As[r0 * LDT + kc0];
  u16* Bsw = &Bs[r0 * LDT + kc0];
  for (int k0 = 0; k0 < K; k0 += 32) {
    __syncthreads();
    uint4 a0 = *(const uint4*)(Ap + k0);
    uint4 a1 = *(const uint4*)(Ap + (long)64 * K + k0);
    uint4 b0 = *(const uint4*)(Bp + k0);
    uint4 b1 = *(const uint4*)(Bp + (long)64 * K + k0);
    *(uint4*)Asw = a0;
    *(uint4*)(Asw + 64 * LDT) = a1;
    *(uint4*)Bsw = b0;
    *(uint4*)(Bsw + 64 * LDT) = b1;
    __syncthreads();
    bf16x8 af[4], bv[4];
#pragma unroll
    for (int m = 0; m < 4; ++m) af[m] = ldfrag(&As[(wr + m * 16 + l15) * LDT + l4 * 8]);
#pragma unroll
    for (int n = 0; n < 4; ++n) bv[n] = ldfrag(&Bs[(wc + n * 16 + l15) * LDT + l4 * 8]);
#pragma unroll
    for (int m = 0; m < 4; ++m)
#pragma unroll
      for (int n = 0; n < 4; ++n) acc[m][n] = mfma16(af[m], bv[n], acc[m][n]);
  }
#pragma unroll
  for (int m = 0; m < 4; ++m)
#pragma unroll
    for (int n = 0; n < 4; ++n)
#pragma unroll
      for (int r = 0; r < 4; ++r) {
        int row = rowbase + wr + m * 16 + l4 * 4 + r;
        int col = colbase + wc + n * 16 + l15;
        if (BF16OUT)
          ((u16*)C)[(long)row * ldc + col] = f2bf(acc[m][n][r]);
        else
          ((float*)C)[(long)row * ldc + col] = acc[m][n][r];
      }
}

// ---------------- RoPE (interleaved pairs), optional score-scale fold ----------------
__global__ __launch_bounds__(256) void rope_kernel(u16* __restrict__ T, int log2H,
                                                   float scale, int total) {
  int p = blockIdx.x * 256 + threadIdx.x;
  if (p >= total) return;
  int i = p & 31;
  int s = (p >> (5 + log2H)) & (S_LEN - 1);
  float freq = exp2f(-(float)i * (13.287712379549449f / 32.0f));  // theta^(-i/32)
  float ang = (float)s * freq;
  float sn, cs;
  sincosf(ang, &sn, &cs);
  uint32_t v = ((uint32_t*)T)[p];
  float e = bf2f((u16)(v & 0xffff)), o = bf2f((u16)(v >> 16));
  float re = (e * cs - o * sn) * scale;
  float ro = (e * sn + o * cs) * scale;
  ((uint32_t*)T)[p] = (uint32_t)f2bf(re) | ((uint32_t)f2bf(ro) << 16);
}

// ---------------- Flash attention (causal, GQA 4:1) ----------------
// grid.x = B*H*(S/64); block = 256 (4 waves x 16 q-rows), KV tile = 64.
__global__ __launch_bounds__(256) void attn_kernel(const u16* __restrict__ Q,
                                                   const u16* __restrict__ Kc,
                                                   const u16* __restrict__ Vc,
                                                   u16* __restrict__ O) {
  int bid = blockIdx.x;
  int qt = bid & 31, h = (bid >> 5) & 31, b = bid >> 10;
  int kvh = h >> 2;
  int qb = qt * 64;
  int tid = threadIdx.x, lane = tid & 63, w = tid >> 6;
  int l15 = lane & 15, l4 = lane >> 4;
  __shared__ u16 Vs[64][72];      // V tile transposed: Vs[d][kv]
  __shared__ u16 Ps[4][16][72];   // per-wave P tile: Ps[w][q][kv]
  long qoff = ((long)b * S_LEN) * 2048 + h * 64;
  long koff = ((long)b * S_LEN) * 512 + kvh * 64;
  int qrow = qb + w * 16 + l15;
  bf16x8 qf0 = ldfrag(Q + qoff + (long)qrow * 2048 + l4 * 8);
  bf16x8 qf1 = ldfrag(Q + qoff + (long)qrow * 2048 + 32 + l4 * 8);
  float m_r[4], l_r[4];
  f32x4 oacc[4] = {};
#pragma unroll
  for (int r = 0; r < 4; ++r) { m_r[r] = -INFINITY; l_r[r] = 0.f; }
  int nt = qt + 1;
  for (int t = 0; t < nt; ++t) {
    int kb = t * 64;
    __syncthreads();
    {  // stage V tile transposed into LDS
      int kv = tid >> 2, d0 = (tid & 3) * 16;
      const u16* vp = Vc + koff + (long)(kb + kv) * 512 + d0;
      uint4 v0 = *(const uint4*)vp;
      uint4 v1 = *(const uint4*)(vp + 8);
      u16 e[16];
      *(uint4*)e = v0;
      *(uint4*)(e + 8) = v1;
#pragma unroll
      for (int i = 0; i < 16; ++i) Vs[d0 + i][kv] = e[i];
    }
    __syncthreads();
    f32x4 sacc[4] = {};
#pragma unroll
    for (int n = 0; n < 4; ++n) {  // scores S[16q][64kv], K frags direct from global
      const u16* kp = Kc + koff + (long)(kb + n * 16 + l15) * 512;
      sacc[n] = mfma16(qf0, ldfrag(kp + l4 * 8), sacc[n]);
      sacc[n] = mfma16(qf1, ldfrag(kp + 32 + l4 * 8), sacc[n]);
    }
    if (t == nt - 1) {  // diagonal tile: causal mask
#pragma unroll
      for (int n = 0; n < 4; ++n) {
        int kvc = kb + n * 16 + l15;
#pragma unroll
        for (int r = 0; r < 4; ++r)
          if (kvc > qb + w * 16 + l4 * 4 + r) sacc[n][r] = -1e30f;
      }
    }
    float fac[4], rs[4];
#pragma unroll
    for (int r = 0; r < 4; ++r) {
      float mx = fmaxf(fmaxf(sacc[0][r], sacc[1][r]), fmaxf(sacc[2][r], sacc[3][r]));
#pragma unroll
      for (int off = 8; off; off >>= 1) mx = fmaxf(mx, __shfl_xor(mx, off));
      float mn = fmaxf(m_r[r], mx);
      fac[r] = __expf(m_r[r] - mn);
      m_r[r] = mn;
      rs[r] = 0.f;
    }
#pragma unroll
    for (int n = 0; n < 4; ++n)
#pragma unroll
      for (int r = 0; r < 4; ++r) {
        float p = __expf(sacc[n][r] - m_r[r]);
        rs[r] += p;
        Ps[w][l4 * 4 + r][n * 16 + l15] = f2bf(p);
      }
#pragma unroll
    for (int r = 0; r < 4; ++r) {
      float s = rs[r];
#pragma unroll
      for (int off = 8; off; off >>= 1) s += __shfl_xor(s, off);
      l_r[r] = l_r[r] * fac[r] + s;
    }
#pragma unroll
    for (int f = 0; f < 4; ++f) {
      oacc[f][0] *= fac[0];
      oacc[f][1] *= fac[1];
      oacc[f][2] *= fac[2];
      oacc[f][3] *= fac[3];
    }
    bf16x8 pa0 = ldfrag(&Ps[w][l15][l4 * 8]);
    bf16x8 pa1 = ldfrag(&Ps[w][l15][32 + l4 * 8]);
#pragma unroll
    for (int f = 0; f < 4; ++f) {
      oacc[f] = mfma16(pa0, ldfrag(&Vs[f * 16 + l15][l4 * 8]), oacc[f]);
      oacc[f] = mfma16(pa1, ldfrag(&Vs[f * 16 + l15][32 + l4 * 8]), oacc[f]);
    }
  }
  float inv[4];
#pragma unroll
  for (int r = 0; r < 4; ++r) inv[r] = 1.f / l_r[r];
#pragma unroll
  for (int f = 0; f < 4; ++f)
#pragma unroll
    for (int r = 0; r < 4; ++r) {
      long orow = (long)b * S_LEN + qb + w * 16 + l4 * 4 + r;
      O[orow * 2048 + h * 64 + f * 16 + l15] = f2bf(oacc[f][r] * inv[r]);
    }
}

// ---------------- launch ----------------
extern "C" void kernel_launch(void* const* d_in, const int* in_sizes, int n_in,
                              void* d_out, int out_size, void* d_ws, size_t ws_size,
                              hipStream_t stream) {
  const float* x = (const float*)d_in[0];
  const float* Wq = (const float*)d_in[1];
  const float* Wk = (const float*)d_in[2];
  const float* Wv = (const float*)d_in[3];
  const float* Wo = (const float*)d_in[4];
  float* out = (float*)d_out;
  char* ws = (char*)d_ws;
  // workspace layout (bytes)
  u16* xb = (u16*)(ws + 0);          // 4096x2048 bf16   (16 MiB)
  u16* WqT = (u16*)(ws + 16777216);  // 2048x2048        (8 MiB)
  u16* WkT = (u16*)(ws + 25165824);  // 512x2048         (2 MiB)
  u16* WvT = (u16*)(ws + 27262976);  // 512x2048         (2 MiB)
  u16* WoT = (u16*)(ws + 29360128);  // 2048x2048        (8 MiB)
  u16* Qs = (u16*)(ws + 37748736);   // 4096x2048        (16 MiB)
  u16* Ks = (u16*)(ws + 54525952);   // 4096x512         (4 MiB)
  u16* Vs = (u16*)(ws + 58720256);   // 4096x512         (4 MiB)
  u16* Os = (u16*)(ws + 62914560);   // 4096x2048        (16 MiB)

  cvt_kernel<<<8192, 256, 0, stream>>>(x, xb, 2097152);
  cvtT_kernel<<<dim3(64, 64), 256, 0, stream>>>(Wq, WqT, 2048, 2048);
  cvtT_kernel<<<dim3(16, 64), 256, 0, stream>>>(Wk, WkT, 2048, 512);
  cvtT_kernel<<<dim3(16, 64), 256, 0, stream>>>(Wv, WvT, 2048, 512);
  cvtT_kernel<<<dim3(64, 64), 256, 0, stream>>>(Wo, WoT, 2048, 2048);
  gemm_bt<1><<<dim3(32, 16), 256, 0, stream>>>(xb, WqT, Qs, 2048, 2048);
  gemm_bt<1><<<dim3(32, 4), 256, 0, stream>>>(xb, WkT, Ks, 2048, 512);
  gemm_bt<1><<<dim3(32, 4), 256, 0, stream>>>(xb, WvT, Vs, 2048, 512);
  rope_kernel<<<16384, 256, 0, stream>>>(Qs, 5, 0.125f, 4194304);  // Q: fold 1/sqrt(64)
  rope_kernel<<<4096, 256, 0, stream>>>(Ks, 3, 1.0f, 1048576);     // K
  attn_kernel<<<2048, 256, 0, stream>>>(Qs, Ks, Vs, Os);
  gemm_bt<0><<<dim3(32, 16), 256, 0, stream>>>(Os, WoT, out, 2048, 2048);
}